// Round 1
// 316.431 us; speedup vs baseline: 1.0910x; 1.0910x over previous
//
#include <hip/hip_runtime.h>
#include <hip/hip_bf16.h>

// Net_22625887715641: fused conv-feats + channel-normalize + 32x32 normalized
// cross-correlation (23x23 shifts, 362x362 templates).
//
// R11 vs R10 (corr 197us, MfmaUtil 34%, Occupancy 27%):
//  Diagnosis: 100+ unified regs (52 VGPR + 48 AGPR acc) -> 4 waves/SIMD ->
//  only 2 blocks/CU resident, so the 768-block grid ran in 1.5 rounds
//  (occupancy 37.5% then 18.75%, avg 28% == measured 27%). Per-y also paid
//  2 barriers + serial staging + cold Af0/Af1 reload (~L2 latency).
//  - NCHUNKS 24 -> 16: grid = 512 = exactly 2 blocks/CU, single round.
//    (16 % 8 == 0 keeps chunk%8==XCD L2 locality; ~1.8MB/XCD footprint.)
//  - sB double-buffered (2x13824B): stage y+1 into buf[(iy+1)&1] while
//    K-loop reads buf[iy&1]; ONE barrier per y (end of iteration covers
//    both read-done and staging-visible hazards). Staging global loads +
//    ds_writes overlap MFMA.
//  - Rolling A prefetch: filtb rows contiguous (12288 = 24*512), Kt+2
//    prefetch unclamped -> Af0/Af1 carry next row's Kt0/Kt1 across the
//    barrier; no per-y A warm-up stall. Tail prefetch overruns <=1KB into
//    prevb (allocated, discarded).
//  - feat/pack/prep unchanged.

typedef unsigned short ushort_t;
typedef unsigned int uint_t;
typedef unsigned char uchar_t;
typedef __attribute__((ext_vector_type(4))) float f32x4;
typedef __attribute__((ext_vector_type(16))) float f32x16;
typedef __attribute__((ext_vector_type(4))) uint_t uint4_t;
typedef __attribute__((ext_vector_type(2))) uint_t uint2_t;

#define EPSF 2.2204460492503131e-16f
#define X1_N (32*384*384)
#define X2_N (32*32*23*23)

// filtb: fp8 [372 rows][48 xb][32 o][8 j]; row = yf+5 (data rows 5..366)
#define FILTB_BYTES (372*48*32*8)
// prevb: fp8 [32 c][385 rows][432 x]; data rows 0..383 cols 0..383; zeros else
#define PREVB_STRIDE 432
#define PREVB_BYTES (32*385*PREVB_STRIDE)
#define ZERO_BYTES ((size_t)FILTB_BYTES + PREVB_BYTES)
// fT2: fp32 [16 chp][45 rows][12] after prevb
#define FT2_ELEMS (16*45*12)

#define YMAX 367            // y-steps 0..366
#define NCHUNKS 16          // 32*16 = 512 blocks = exactly 2/CU, one round
#define INV_AREA (1.0f/131044.0f)

// sB bytes: [dyb 4][copy 8][432]; copy stride 432 (16-mult, 48B bank stagger)
#define SB_COPY_B 432
#define SB_DYB_B  (8*SB_COPY_B)     // 3456
#define SB_BYTES  (4*SB_DYB_B)      // 13824 B per buffer; x2 double-buffer

// ---------------------------------------------------------------------------
// fp32 -> fp8 e4m3 (OCP), RNE, input assumed in [0, 448).
// ---------------------------------------------------------------------------
__device__ __forceinline__ uint_t f32_to_e4m3(float f) {
  if (f < 0.015625f)                         // subnormal: m * 2^-9
    return (uint_t)__float2int_rn(f * 512.0f);
  uint_t b = __builtin_bit_cast(uint_t, f);
  int e = (int)(b >> 23) - 127;
  uint_t m = b & 0x7FFFFFu;
  uint_t keep = m >> 20;
  uint_t rest = m & 0xFFFFFu;
  keep += (rest > 0x80000u) || (rest == 0x80000u && (keep & 1u));
  if (keep == 8u) { keep = 0u; e += 1; }
  if (e > 8) return 0x7Eu;                   // saturate 448
  return (uint_t)(((e + 7) << 3) | keep);
}

// ---------------------------------------------------------------------------
// Prep: pack filters to [chp][45][12] (rows 16B-aligned, b-contiguous).
// ---------------------------------------------------------------------------
__global__ void prep_kernel(const float* __restrict__ ft, const float* __restrict__ fn,
                            float* __restrict__ fT2)
{
  const int e = blockIdx.x * 256 + threadIdx.x;
  if (e < FT2_ELEMS) {
    const int chp = e / 540;
    const int rem = e - chp * 540;
    const int row = rem / 12;
    const int j = rem - row * 12;
    float v = 0.f;
    if (j < 11) {
      if (row < 33)      v = ft[chp * 363 + row * 11 + j];        // row = t*11+a
      else if (row < 44) v = fn[chp * 121 + (row - 33) * 11 + j]; // row-33 = a
    }
    fT2[e] = v;
  }
}

// ---------------------------------------------------------------------------
// Stage 1: thread = (ch-pair chp) x (16-px row). Block 128 = 8 rows x 16 chp.
// mode 0: x -> x1 (fp32). mode 1: xprev -> prevb (fp8 e4m3).
// ---------------------------------------------------------------------------
__global__ __launch_bounds__(128, 4) void feat_kernel(
    const float* __restrict__ xcur, const float* __restrict__ xprev,
    const float* __restrict__ fT2,
    float* __restrict__ out_x1, uchar_t* __restrict__ prevb)
{
  __shared__ float sPx[3 * 18 * 28];
  const int tid = threadIdx.x;
  const int chp = tid & 15;
  const int r = tid >> 4;              // 0..7
  const int j0 = blockIdx.x * 16;
  const int i0 = blockIdx.y * 8;
  const int i = i0 + r;
  const int mode = blockIdx.z;
  const float* __restrict__ xin = mode ? xprev : xcur;

  for (int e = tid; e < 3 * 18 * 26; e += 128) {
    const int t = e / 468;
    const int rem = e - t * 468;
    const int ri = rem / 26;
    const int ci = rem - ri * 26;
    sPx[(t * 18 + ri) * 28 + ci] = xin[((size_t)t * 394 + i0 + ri) * 394 + j0 + ci];
  }
  __syncthreads();

  const float* __restrict__ fbase = fT2 + chp * 540;

  float accT[16], accN[16];
#pragma unroll
  for (int p = 0; p < 16; ++p) { accT[p] = 0.f; accN[p] = 0.f; }

#pragma unroll
  for (int t = 0; t < 3; ++t) {
    for (int a = 0; a < 11; ++a) {
      const float* row = &sPx[(t * 18 + r + a) * 28];
      float wv[26];
#pragma unroll
      for (int k = 0; k < 6; ++k) {
        const f32x4 q = *(const f32x4*)(row + 4 * k);
        wv[4 * k + 0] = q[0]; wv[4 * k + 1] = q[1];
        wv[4 * k + 2] = q[2]; wv[4 * k + 3] = q[3];
      }
      wv[24] = row[24]; wv[25] = row[25];

      const float* fr = fbase + (t * 11 + a) * 12;
      const f32x4 fq0 = *(const f32x4*)(fr);
      const f32x4 fq1 = *(const f32x4*)(fr + 4);
      const f32x4 fq2 = *(const f32x4*)(fr + 8);
      float fv[12];
#pragma unroll
      for (int k = 0; k < 4; ++k) { fv[k] = fq0[k]; fv[4+k] = fq1[k]; fv[8+k] = fq2[k]; }
      float fv2[12];
      if (t == 2) {
        const float* fr2 = fbase + (33 + a) * 12;
        const f32x4 g0 = *(const f32x4*)(fr2);
        const f32x4 g1 = *(const f32x4*)(fr2 + 4);
        const f32x4 g2 = *(const f32x4*)(fr2 + 8);
#pragma unroll
        for (int k = 0; k < 4; ++k) { fv2[k] = g0[k]; fv2[4+k] = g1[k]; fv2[8+k] = g2[k]; }
      }

#pragma unroll
      for (int b = 0; b < 11; ++b) {
        const float fT = fv[b];
#pragma unroll
        for (int p = 0; p < 16; ++p) accT[p] = fmaf(wv[b + p], fT, accT[p]);
        if (t == 2) {
          const float fN = fv2[b];
#pragma unroll
          for (int p = 0; p < 16; ++p) accN[p] = fmaf(wv[b + p], fN, accN[p]);
        }
      }
    }
  }

  float o0[16], o1[16];
#pragma unroll
  for (int p = 0; p < 16; ++p) {
    const float vT = fmaxf(accT[p], 0.f) * 0.5f;   // temp: relu(conv)/2
    const float vN = fmaxf(accN[p], 0.f);
    float s = vT + vN;
    s += __shfl_xor(s, 1);  s += __shfl_xor(s, 2);
    s += __shfl_xor(s, 4);  s += __shfl_xor(s, 8);
    const float inv = 1.f / (s + EPSF);
    o0[p] = vT * inv;
    o1[p] = vN * inv;
  }

  if (mode == 0) {
#pragma unroll
    for (int q = 0; q < 4; ++q) {
      f32x4 v0 = {o0[4*q], o0[4*q+1], o0[4*q+2], o0[4*q+3]};
      f32x4 v1 = {o1[4*q], o1[4*q+1], o1[4*q+2], o1[4*q+3]};
      *(f32x4*)(out_x1 + (size_t)chp * 147456 + i * 384 + j0 + 4 * q) = v0;
      *(f32x4*)(out_x1 + (size_t)(chp + 16) * 147456 + i * 384 + j0 + 4 * q) = v1;
    }
  } else {
    uint4_t u0, u1;
#pragma unroll
    for (int q = 0; q < 4; ++q) {
      u0[q] = f32_to_e4m3(o0[4*q]) | (f32_to_e4m3(o0[4*q+1]) << 8) |
              (f32_to_e4m3(o0[4*q+2]) << 16) | (f32_to_e4m3(o0[4*q+3]) << 24);
      u1[q] = f32_to_e4m3(o1[4*q]) | (f32_to_e4m3(o1[4*q+1]) << 8) |
              (f32_to_e4m3(o1[4*q+2]) << 16) | (f32_to_e4m3(o1[4*q+3]) << 24);
    }
    *(uint4_t*)(prevb + ((size_t)chp * 385 + i) * PREVB_STRIDE + j0) = u0;
    *(uint4_t*)(prevb + ((size_t)(chp + 16) * 385 + i) * PREVB_STRIDE + j0) = u1;
  }
}

// ---------------------------------------------------------------------------
// Pack x1 (fp32, cropped) into filtb fp8 MFMA-A layout; coalesced 8B writes.
// ---------------------------------------------------------------------------
__global__ __launch_bounds__(256) void pack_kernel(
    const float* __restrict__ x1, uchar_t* __restrict__ filtb)
{
  const int e = blockIdx.x * 256 + threadIdx.x;
  if (e >= 362 * 46 * 32) return;
  const int o = e & 31;
  const int q = e >> 5;
  const int xb = q % 46;
  const int rowr = q / 46 + 5;          // 5..366
  const int i = rowr + 6;               // 11..372
  const int j0 = 11 + xb * 8;
  const float* src = x1 + (size_t)o * 147456 + i * 384 + j0;
  uint_t w0 = 0, w1 = 0;
#pragma unroll
  for (int k = 0; k < 4; ++k) {
    w0 |= f32_to_e4m3((j0 + k     <= 372) ? src[k]     : 0.f) << (8 * k);
    w1 |= f32_to_e4m3((j0 + 4 + k <= 372) ? src[4 + k] : 0.f) << (8 * k);
  }
  uint2_t u = {w0, w1};
  *(uint2_t*)(filtb + (((size_t)(rowr * 48 + xb) * 32 + o) << 3)) = u;
}

// ---------------------------------------------------------------------------
// Stage 2: correlation via 32x32x16 fp8 MFMA.
//   out[o,c,dy,dx] = sum_{y,x} filt[o][y-dy_a][x] * prev[c][y+6*dy_b][x+dx]
//   M=192=(dy_a 6)x(o 32); N=96: n = dyb*24+dx (dx 0..22, 23=pad); K=(y, x).
// Block 384 thr = 6 waves, ONE channel; wave w = dy_a w, all 3 N-tiles of 32.
// A-operand row = y-w+5 is WAVE-UNIFORM -> one coalesced 8B load/lane/Kt.
// Operand map (32x32x16): m/n = lane&31, k = (lane>>5)*8 + j.
// C/D map: col = lane&31, row = (reg&3)+8*(reg>>2)+4*(lane>>5).
// Double-buffered sB: stage y+1 while computing y; one barrier per y.
// ---------------------------------------------------------------------------
__global__ __launch_bounds__(384, 4) void corr_kernel(
    const uchar_t* __restrict__ filtb, const uchar_t* __restrict__ prevb,
    float* __restrict__ x2)
{
  __shared__ uint_t sB[2 * (SB_BYTES / 4)];    // 27648 B

  const int tid = threadIdx.x;
  const int lane = tid & 63;
  const int w = tid >> 6;                // 0..5 = dy_a
  const int kg = lane >> 5;              // k-group 0..1
  const int nn = lane & 31;              // n (or o) within tile

  const int ch = blockIdx.x / NCHUNKS;         // 0..31
  const int chunk = blockIdx.x % NCHUNKS;      // 0..15; %8 == XCD
  const int y0 = (chunk * YMAX) / NCHUNKS;     // balanced 22-23 y-steps
  const int y1 = ((chunk + 1) * YMAX) / NCHUNKS;

  // Per-lane B-fragment byte offsets (Kt*16 added at use). All 8B-aligned.
  int boffB[3];
#pragma unroll
  for (int nt = 0; nt < 3; ++nt) {
    const int n = nt * 32 + nn;          // 0..95
    const int dyb = n / 24;
    const int dxr = n - 24 * dyb;
    const int dx = (dxr < 23) ? dxr : 22;      // pad lane reads valid data
    const int s = dx & 7;
    boffB[nt] = dyb * SB_DYB_B + s * SB_COPY_B + (dx >> 3) * 8 + kg * 8;
  }

  // Staging: 104 tasks (dyb = t/26, 16B group g = t%26); 24B src window each.
  const bool st_act = (tid < 104);
  const int sdyb = st_act ? (tid / 26) : 0;
  const int sg = tid - 26 * (st_act ? (tid / 26) : 0);
  const uchar_t* srcbase = prevb + ((size_t)(ch * 385 + 6 * sdyb)) * PREVB_STRIDE;
  const int dstoff = sdyb * (SB_DYB_B / 4) + 4 * sg;   // word offset in buffer

  uint_t st0 = 0, st1 = 0, st2 = 0, st3 = 0, st4 = 0, st5 = 0;

  // load prevb row for y-step yy into st regs
  auto load_st = [&](int yy) {
    const uint_t* sw = (const uint_t*)(srcbase + (size_t)yy * PREVB_STRIDE) + 4 * sg;
    const uint4_t lo = *(const uint4_t*)(sw);
    const uint2_t hi = *(const uint2_t*)(sw + 4);
    st0 = lo.x; st1 = lo.y; st2 = lo.z; st3 = lo.w; st4 = hi.x; st5 = hi.y;
  };

  // expand st regs into 8 byte-shifted copies in buffer buf
  auto write_shift = [&](int buf) {
    uint_t* dst = sB + buf * (SB_BYTES / 4) + dstoff;
    const uint_t wd[6] = {st0, st1, st2, st3, st4, st5};
#pragma unroll
    for (int s = 0; s < 8; ++s) {
      const int off = s >> 2;
      const int b = (s & 3) * 8;
      uint4_t v;
      if (b == 0) {
        v = uint4_t{wd[off], wd[off + 1], wd[off + 2], wd[off + 3]};
      } else {
        v = uint4_t{(wd[off]     >> b) | (wd[off + 1] << (32 - b)),
                    (wd[off + 1] >> b) | (wd[off + 2] << (32 - b)),
                    (wd[off + 2] >> b) | (wd[off + 3] << (32 - b)),
                    (wd[off + 3] >> b) | (wd[off + 4] << (32 - b))};
      }
      *(uint4_t*)(dst + s * (SB_COPY_B / 4)) = v;
    }
  };

  f32x16 acc[3];
#pragma unroll
  for (int nt = 0; nt < 3; ++nt)
#pragma unroll
    for (int r = 0; r < 16; ++r) acc[nt][r] = 0.f;

  // Prologue: stage y0 into buf 0; preload y0+1 into regs.
  if (st_act) {
    load_st(y0);
    write_shift(0);
    if (y0 + 1 < y1) load_st(y0 + 1);
  }

  // A stream: rows are contiguous in filtb (row stride 12288 = 24 Kt * 512B),
  // so Af0/Af1 roll across y-iterations without re-warm.
  const uchar_t* aptr = filtb + (size_t)(y0 - w + 5) * 12288 + kg * 256 + nn * 8;
  long Af0 = *(const long*)(aptr);
  long Af1 = *(const long*)(aptr + 512);

  __syncthreads();                       // buf0 staged

  for (int y = y0; y < y1; ++y) {
    const int pb = (y - y0) & 1;         // buffer being read this iteration

    // Stage y+1 into the other buffer (read during y-1; all waves passed the
    // end-of-(y-1) barrier, so it's free). Then prefetch y+2 into regs —
    // a full K-loop of latency cover.
    if (st_act && y + 1 < y1) write_shift(pb ^ 1);
    if (st_act && y + 2 < y1) load_st(y + 2);

    const char* sBrd = (const char*)sB + pb * SB_BYTES;

    // K-loop: 24 Kt16 steps; A prefetched 2 deep (rolling, unclamped), B 1 deep.
    long Af2, Bf[3], Bfn[3];
#pragma unroll
    for (int nt = 0; nt < 3; ++nt)
      Bf[nt] = *(const long*)(sBrd + boffB[nt]);

#pragma unroll
    for (int Kt = 0; Kt < 24; ++Kt) {
      Af2 = *(const long*)(aptr + ((Kt + 2) << 9));   // rolls into next row
      const int Ktb = (Kt + 1 < 24) ? Kt + 1 : 23;
#pragma unroll
      for (int nt = 0; nt < 3; ++nt)
        Bfn[nt] = *(const long*)(sBrd + boffB[nt] + (Ktb << 4));
#pragma unroll
      for (int nt = 0; nt < 3; ++nt)
        acc[nt] = __builtin_amdgcn_mfma_f32_32x32x16_fp8_fp8(
            Af0, Bf[nt], acc[nt], 0, 0, 0);
      Af0 = Af1; Af1 = Af2;
#pragma unroll
      for (int nt = 0; nt < 3; ++nt) Bf[nt] = Bfn[nt];
    }
    aptr += 12288;                       // next y: row += 1 (Af0/Af1 now hold it)

    __syncthreads();                     // staging y+1 visible; reads of pb done
  }

  // Epilogue: scale partials, atomically accumulate into x2[o][c][dy][dx].
#pragma unroll
  for (int nt = 0; nt < 3; ++nt) {
    const int n = nt * 32 + nn;
    const int dyb = n / 24;
    const int dxr = n - 24 * dyb;
    if (dxr < 23) {
      const int dy = w + 6 * dyb;
      if (dy <= 22) {
#pragma unroll
        for (int r = 0; r < 16; ++r) {
          const int o = (r & 3) + 8 * (r >> 2) + 4 * kg;   // C/D row
          atomicAdd(&x2[((o * 32 + ch) * 23 + dy) * 23 + dxr],
                    acc[nt][r] * INV_AREA);
        }
      }
    }
  }
}

// ---------------------------------------------------------------------------
extern "C" void kernel_launch(void* const* d_in, const int* in_sizes, int n_in,
                              void* d_out, int out_size, void* d_ws, size_t ws_size,
                              hipStream_t stream)
{
  const float* x     = (const float*)d_in[0];   // [3][394][394]
  const float* xprev = (const float*)d_in[1];
  const float* ft    = (const float*)d_in[2];   // [16][3][11][11]
  const float* fn    = (const float*)d_in[3];   // [16][1][11][11]
  float* out = (float*)d_out;

  uchar_t* filtb = (uchar_t*)d_ws;
  uchar_t* prevb = filtb + FILTB_BYTES;
  float* fT2 = (float*)(prevb + PREVB_BYTES);

  // Zero packed buffers (zero padding) and the x2 accumulator.
  hipMemsetAsync(d_ws, 0, ZERO_BYTES, stream);
  hipMemsetAsync(out + X1_N, 0, (size_t)X2_N * sizeof(float), stream);

  prep_kernel<<<dim3((FT2_ELEMS + 255) / 256), 256, 0, stream>>>(ft, fn, fT2);
  feat_kernel<<<dim3(24, 48, 2), 128, 0, stream>>>(x, xprev, fT2, out, prevb);
  pack_kernel<<<dim3((362 * 46 * 32 + 255) / 256), 256, 0, stream>>>(out, filtb);
  corr_kernel<<<dim3(32 * NCHUNKS), 384, 0, stream>>>(filtb, prevb, out + X1_N);
}